// Round 1
// baseline (140.974 us; speedup 1.0000x reference)
//
#include <hip/hip_runtime.h>

typedef __attribute__((ext_vector_type(8))) short short8;
typedef __attribute__((ext_vector_type(4))) float f32x4;
typedef __attribute__((ext_vector_type(4))) float float4v;
typedef __attribute__((ext_vector_type(4))) unsigned short ushort4v;
typedef unsigned int __attribute__((may_alias)) u32ma;

#define B_   4
#define LQ   4096
#define LKV  4096
#define E_   1024
#define H_   128
#define NSPLIT 4
#define KVSPL (LKV / NSPLIT)   // 1024
#define NT    (KVSPL / 64)     // 16
#define WELEM (H_ * E_)        // 131072 elements per weight matrix

static __device__ __forceinline__ unsigned short bf16_rne(float f) {
    unsigned int u = __float_as_uint(f);
    u += 0x7fffu + ((u >> 16) & 1u);
    return (unsigned short)(u >> 16);
}
static __device__ __forceinline__ float bf16_tof(unsigned short h) {
    return __uint_as_float(((unsigned int)h) << 16);
}
static __device__ __forceinline__ f32x4 mfma16(short8 a, short8 b, f32x4 c) {
    return __builtin_amdgcn_mfma_f32_16x16x32_bf16(a, b, c, 0, 0, 0);
}
static __device__ __forceinline__ void gload16(const unsigned short* g, unsigned short* l) {
    __builtin_amdgcn_global_load_lds(
        (const __attribute__((address_space(1))) unsigned int*)g,
        (__attribute__((address_space(3))) unsigned int*)l, 16, 0, 0);
}

// ---------------------------------------------------------------------------
// One-time W conversion: f32 -> split bf16 (hi+lo for Wq/Wk, hi for Wv),
// stored PRE-SWIZZLED: Wsw[kb][c]{8 elems} = W[h=c>>3][kb*64 + ((c&7)^(h&7))*8 ..]
// so proj can global_load_lds linearly and read with the XOR pattern.
// ---------------------------------------------------------------------------
__global__ __launch_bounds__(256) void convert_w_kernel(
    const float* __restrict__ Wq, const float* __restrict__ Wk, const float* __restrict__ Wv,
    unsigned short* __restrict__ wqh, unsigned short* __restrict__ wql,
    unsigned short* __restrict__ wkh, unsigned short* __restrict__ wkl,
    unsigned short* __restrict__ wvh)
{
    const int kb = blockIdx.x;       // 0..15
    const int which = blockIdx.y;    // 0:Wq 1:Wk 2:Wv
    const float* W = (which == 0) ? Wq : (which == 1) ? Wk : Wv;
    unsigned short* outh = (which == 0) ? wqh : (which == 1) ? wkh : wvh;
    unsigned short* outl = (which == 0) ? wql : wkl;
    const int t = threadIdx.x;
#pragma unroll
    for (int i = 0; i < 4; ++i) {
        const int c = t * 4 + i;                 // chunk 0..1023
        const int h = c >> 3;
        const int k = kb * 64 + (((c & 7) ^ (h & 7)) * 8);
        const float* src = W + (size_t)h * E_ + k;
        float4v v0 = *(const float4v*)(src);
        float4v v1 = *(const float4v*)(src + 4);
        short8 hi, lo;
#pragma unroll
        for (int e = 0; e < 4; ++e) {
            unsigned short h0 = bf16_rne(v0[e]);
            unsigned short h1 = bf16_rne(v1[e]);
            hi[e] = (short)h0; hi[e + 4] = (short)h1;
            lo[e] = (short)bf16_rne(v0[e] - bf16_tof(h0));
            lo[e + 4] = (short)bf16_rne(v1[e] - bf16_tof(h1));
        }
        *(short8*)&outh[(size_t)kb * 8192 + (size_t)c * 8] = hi;
        if (which < 2) *(short8*)&outl[(size_t)kb * 8192 + (size_t)c * 8] = lo;
    }
}

// ---------------------------------------------------------------------------
// Projection GEMM (unchanged). 256 blocks x 512 thr (8 waves).
// ---------------------------------------------------------------------------
__global__ __launch_bounds__(512, 1) void proj_kernel(
    const float* __restrict__ x, const float* __restrict__ z,
    const unsigned short* __restrict__ wqh, const unsigned short* __restrict__ wql,
    const unsigned short* __restrict__ wkh, const unsigned short* __restrict__ wkl,
    const unsigned short* __restrict__ wvh,
    unsigned short* __restrict__ qhi, unsigned short* __restrict__ qlo,
    unsigned short* __restrict__ khi, unsigned short* __restrict__ klo,
    unsigned short* __restrict__ vt)
{
    const int bid = blockIdx.x;
    const bool qmode = bid < 128;
    const int m0 = (qmode ? bid : bid - 128) * 128;
    const float* Asrc = qmode ? x : z;
    const unsigned short* W1h = qmode ? wqh : wkh;
    const unsigned short* W1l = qmode ? wql : wkl;

    const int t = threadIdx.x;
    const int w = t >> 6, l = t & 63, lg = (l >> 4) & 3, ll = l & 15;
    const int mw = w & 3, nw = w >> 2;

    __shared__ unsigned short Ah[8192];        // 16 KiB  [128 r][64 k] swizzled
    __shared__ unsigned short Al[8192];        // 16 KiB
    __shared__ unsigned short Wh[2][8192];     // 32 KiB  [128 h][64 k] swizzled
    __shared__ unsigned short Wl[2][8192];     // 32 KiB
    __shared__ unsigned short Wv2[2][8192];    // 32 KiB (kv-mode only)

    // A prefetch: thread owns row ar = t>>2, quarter aq = t&3 (16 f32)
    const int ar = t >> 2, aq = t & 3;
    float4v ra[4];
    auto loadA = [&](int e0) {
        const float* p = Asrc + (size_t)(m0 + ar) * E_ + e0 + aq * 16;
#pragma unroll
        for (int i = 0; i < 4; ++i) ra[i] = *(const float4v*)(p + i * 4);
    };
    auto writeA = [&]() {
#pragma unroll
        for (int half = 0; half < 2; ++half) {
            short8 hi, lo;
#pragma unroll
            for (int e = 0; e < 4; ++e) {
                float v0 = ra[2 * half][e];
                float v1 = ra[2 * half + 1][e];
                unsigned short h0 = bf16_rne(v0);
                unsigned short h1 = bf16_rne(v1);
                hi[e] = (short)h0; hi[e + 4] = (short)h1;
                lo[e] = (short)bf16_rne(v0 - bf16_tof(h0));
                lo[e + 4] = (short)bf16_rne(v1 - bf16_tof(h1));
            }
            const int j = 2 * aq + half;
            const int off = ar * 64 + ((j ^ (ar & 7)) * 8);
            *(short8*)&Ah[off] = hi;
            *(short8*)&Al[off] = lo;
        }
    };
    auto issueW = [&](int kb, int bsel) {
#pragma unroll
        for (int i = 0; i < 2; ++i) {
            const int cbase = w * 128 + i * 64;
            const size_t so = (size_t)kb * 8192 + (size_t)(cbase + l) * 8;
            gload16(W1h + so, &Wh[bsel][(size_t)cbase * 8]);
            gload16(W1l + so, &Wl[bsel][(size_t)cbase * 8]);
            if (!qmode) gload16(wvh + so, &Wv2[bsel][(size_t)cbase * 8]);
        }
    };

    f32x4 acc[2][4], accv[2][4];
    const f32x4 zz = {0.f, 0.f, 0.f, 0.f};
#pragma unroll
    for (int rf = 0; rf < 2; ++rf)
#pragma unroll
        for (int cf = 0; cf < 4; ++cf) { acc[rf][cf] = zz; accv[rf][cf] = zz; }

    issueW(0, 0);
    loadA(0);
    writeA();
    __syncthreads();   // drains vmcnt (W0 in LDS) + lgkm (A0 in LDS)

    for (int kb = 0; kb < 16; ++kb) {
        const int bsel = kb & 1;
        if (kb < 15) { issueW(kb + 1, bsel ^ 1); loadA((kb + 1) * 64); }

#pragma unroll
        for (int ks = 0; ks < 2; ++ks) {
            short8 a_h[2], a_l[2];
#pragma unroll
            for (int rf = 0; rf < 2; ++rf) {
                const int r = mw * 32 + rf * 16 + ll;
                const int off = r * 64 + (((ks * 4 + lg) ^ (ll & 7)) * 8);
                a_h[rf] = *(const short8*)&Ah[off];
                a_l[rf] = *(const short8*)&Al[off];
            }
#pragma unroll
            for (int cf = 0; cf < 4; ++cf) {
                const int hrow = nw * 64 + cf * 16 + ll;
                const int off = hrow * 64 + (((ks * 4 + lg) ^ (ll & 7)) * 8);
                short8 bh = *(const short8*)&Wh[bsel][off];
                short8 bl = *(const short8*)&Wl[bsel][off];
#pragma unroll
                for (int rf = 0; rf < 2; ++rf) {
                    acc[rf][cf] = mfma16(a_h[rf], bh, acc[rf][cf]);
                    acc[rf][cf] = mfma16(a_h[rf], bl, acc[rf][cf]);
                    acc[rf][cf] = mfma16(a_l[rf], bh, acc[rf][cf]);
                }
                if (!qmode) {
                    short8 bv = *(const short8*)&Wv2[bsel][off];
#pragma unroll
                    for (int rf = 0; rf < 2; ++rf)
                        accv[rf][cf] = mfma16(a_h[rf], bv, accv[rf][cf]);
                }
            }
        }
        __syncthreads();             // all waves done reading Ah/Al + W(kb+1) drained
        if (kb < 15) {
            writeA();                // A(kb+1) -> LDS
            __syncthreads();         // writes visible
        }
    }

    // epilogue: D layout col(ll)=W-row h, row(4lg+j)=A-row m  [verified R1-R3]
#pragma unroll
    for (int rf = 0; rf < 2; ++rf)
#pragma unroll
        for (int cf = 0; cf < 4; ++cf)
#pragma unroll
            for (int j = 0; j < 4; ++j) {
                const int m = m0 + mw * 32 + rf * 16 + 4 * lg + j;
                const int h = nw * 64 + cf * 16 + ll;
                const float val = acc[rf][cf][j];
                unsigned short hi = bf16_rne(val);
                unsigned short lo = bf16_rne(val - bf16_tof(hi));
                const size_t o = (size_t)m * H_ + h;
                if (qmode) {
                    qhi[o] = hi; qlo[o] = lo;
                } else {
                    khi[o] = hi; klo[o] = lo;
                    const int b = m >> 12, kv = m & 4095;
                    vt[(size_t)b * ((size_t)H_ * LKV) + (size_t)h * LKV + kv] =
                        bf16_rne(accv[rf][cf][j]);
                }
            }
}

// ---------------------------------------------------------------------------
// Flash attention, swapped-operand form. RESTRUCTURED for 2 blocks/CU:
// 512 blocks (4 bb x 32 qt x 4 split), 8 waves x 16 q-rows each.
// LDS 80 KiB: K hi/lo single-buffer (32K) + V double-buffer (32K) + Pl (16K).
// Raw s_barrier schedule (2/tile): V(t+1) issued at tile top (hidden under
// whole tile), K(t+1) issued after QK^T barrier (hidden under PV).
// ---------------------------------------------------------------------------
__global__ __launch_bounds__(512, 4) void attn_kernel(
    const unsigned short* __restrict__ qhi, const unsigned short* __restrict__ qlo,
    const unsigned short* __restrict__ khi, const unsigned short* __restrict__ klo,
    const unsigned short* __restrict__ vt,
    float* __restrict__ Opart, float* __restrict__ msb, float* __restrict__ lsb)
{
    const int blk = blockIdx.x;          // 512 blocks
    const int bb = blk & 3;
    const int qt = (blk >> 2) & 31;
    const int split = blk >> 7;          // 0..3
    const int t = threadIdx.x;
    const int w = t >> 6, l = t & 63, lg = (l >> 4) & 3, ll = l & 15;

    __shared__ unsigned short Kh[8192];        // 16 KiB [64 kv][128 h] swizzled
    __shared__ unsigned short Kl[8192];        // 16 KiB
    __shared__ unsigned short Vb[2][8192];     // 32 KiB [128 h][64 kv] swizzled, dbuf
    __shared__ unsigned short Pl[8][16][64];   // 16 KiB per-wave P staging

    const float CSC = 11.313708498984761f * 1.4426950408889634f;

    // Q fragments: wave owns 16 q rows (= one MFMA B operand per ks block)
    short8 qh[4], ql[4];
    {
        const size_t qrow = (size_t)(bb * LQ + qt * 128 + w * 16 + ll) * H_;
#pragma unroll
        for (int ks = 0; ks < 4; ++ks) {
            qh[ks] = *(const short8*)(qhi + qrow + ks * 32 + lg * 8);
            ql[ks] = *(const short8*)(qlo + qrow + ks * 32 + lg * 8);
        }
    }

    const int kv_base = split * KVSPL;
    const unsigned short* khb = khi + (size_t)bb * LKV * H_;
    const unsigned short* klb = klo + (size_t)bb * LKV * H_;
    const unsigned short* vbg = vt + (size_t)bb * ((size_t)H_ * LKV);

    auto issue_K = [&](int kv0) {
#pragma unroll
        for (int ci = 0; ci < 2; ++ci) {
            const int chunk = w * 2 + ci;              // 0..15
            const int row = chunk * 4 + (l >> 4);      // kv row 0..63
            const int c = l & 15;                      // col-chunk
            const size_t so = (size_t)(kv0 + row) * H_ + ((c ^ (row & 7)) * 8);
            gload16(khb + so, &Kh[chunk * 512]);
            gload16(klb + so, &Kl[chunk * 512]);
        }
    };
    auto issue_V = [&](int kv0, int bs) {
#pragma unroll
        for (int ci = 0; ci < 2; ++ci) {
            const int chunk = w * 2 + ci;              // 0..15
            const int row = chunk * 8 + (l >> 3);      // h row 0..127
            const int c = l & 7;                       // col-chunk
            gload16(vbg + (size_t)row * LKV + kv0 + ((c ^ (row & 7)) * 8),
                    &Vb[bs][chunk * 512]);
        }
    };

    f32x4 O[8];
    const f32x4 zz = {0.f, 0.f, 0.f, 0.f};
#pragma unroll
    for (int f = 0; f < 8; ++f) O[f] = zz;
    float mold = -1e30f;
    float lsum = 0.f;

    issue_K(kv_base);
    issue_V(kv_base, 0);
    asm volatile("s_waitcnt vmcnt(0)" ::: "memory");
    __builtin_amdgcn_s_barrier();

    int vsel = 0;
    for (int ti = 0; ti < NT; ++ti) {
        // Prefetch next V into the spare buffer (its previous readers finished
        // at the end-of-tile barrier of ti-1). Hidden under this whole tile.
        if (ti + 1 < NT) issue_V(kv_base + (ti + 1) * 64, vsel ^ 1);
        __builtin_amdgcn_sched_barrier(0);

        // ---- QK^T (reads Kh/Kl) ----
        f32x4 S[4];
#pragma unroll
        for (int a = 0; a < 4; ++a) S[a] = zz;
#pragma unroll
        for (int ks = 0; ks < 4; ++ks) {
#pragma unroll
            for (int a = 0; a < 4; ++a) {
                const int row = a * 16 + ll;
                const int off = row * 128 + (((ks * 4 + lg) ^ (ll & 7)) * 8);
                short8 kh  = *(const short8*)&Kh[off];
                short8 kl2 = *(const short8*)&Kl[off];
                S[a] = mfma16(kh,  qh[ks], S[a]);
                S[a] = mfma16(kh,  ql[ks], S[a]);
                S[a] = mfma16(kl2, qh[ks], S[a]);
            }
        }

        // ---- online softmax (per-wave; writes Pl[w]) ----
        float mx = S[0][0];
#pragma unroll
        for (int a = 0; a < 4; ++a)
#pragma unroll
            for (int j = 0; j < 4; ++j) mx = fmaxf(mx, S[a][j]);
        mx = fmaxf(mx, __shfl_xor(mx, 16));
        mx = fmaxf(mx, __shfl_xor(mx, 32));
        const float mn = fmaxf(mold, mx * CSC);
        const float corr = exp2f(mold - mn);
        float ps = 0.f;
#pragma unroll
        for (int a = 0; a < 4; ++a) {
            float p0 = exp2f(fmaf(S[a][0], CSC, -mn));
            float p1 = exp2f(fmaf(S[a][1], CSC, -mn));
            float p2 = exp2f(fmaf(S[a][2], CSC, -mn));
            float p3 = exp2f(fmaf(S[a][3], CSC, -mn));
            ps += (p0 + p1) + (p2 + p3);
            unsigned int pk0, pk1;
            asm("v_cvt_pk_bf16_f32 %0, %1, %2" : "=v"(pk0) : "v"(p0), "v"(p1));
            asm("v_cvt_pk_bf16_f32 %0, %1, %2" : "=v"(pk1) : "v"(p2), "v"(p3));
            u32ma* pd = (u32ma*)&Pl[w][0][0];
            const int di = ll * 32 + (((2 * a + (lg >> 1)) ^ (ll & 7)) * 4) + 2 * (lg & 1);
            pd[di] = pk0;
            pd[di + 1] = pk1;
        }
        ps += __shfl_xor(ps, 16);
        ps += __shfl_xor(ps, 32);
        lsum = lsum * corr + ps;
        mold = mn;
#pragma unroll
        for (int f = 0; f < 8; ++f) O[f] *= corr;

        // All our LDS ops (QK^T reads + P writes) retired; release K buffer.
        asm volatile("s_waitcnt lgkmcnt(0)" ::: "memory");
        __builtin_amdgcn_sched_barrier(0);
        __builtin_amdgcn_s_barrier();                    // (1) K region free
        if (ti + 1 < NT) issue_K(kv_base + (ti + 1) * 64);
        __builtin_amdgcn_sched_barrier(0);

        // ---- PV (reads Vb[vsel] + Pl[w]) ----
#pragma unroll
        for (int ks = 0; ks < 2; ++ks) {
            short8 pb = *(const short8*)&Pl[w][ll][((ks * 4 + lg) ^ (ll & 7)) * 8];
#pragma unroll
            for (int f = 0; f < 8; ++f) {
                const int row = f * 16 + ll;
                short8 va = *(const short8*)&Vb[vsel][row * 64
                                                     + (((ks * 4 + lg) ^ (ll & 7)) * 8)];
                O[f] = mfma16(va, pb, O[f]);
            }
        }

        // Drain prefetches (V had the whole tile, K had the PV phase to land),
        // and make sure every wave is done reading Vb[vsel] before reuse.
        asm volatile("s_waitcnt vmcnt(0)" ::: "memory");
        __builtin_amdgcn_sched_barrier(0);
        __builtin_amdgcn_s_barrier();                    // (2)
        vsel ^= 1;
    }

    // epilogue: O[f][j] holds h = f*16 + 4*lg + j, q = qt*128 + w*16 + ll
    const size_t ob = (((size_t)split * 4 + bb) * 32 + qt) * 8 + w;
#pragma unroll
    for (int f = 0; f < 8; ++f)
        *(float4v*)&Opart[(ob * 8 + f) * 256 + l * 4] = O[f];

    if (lg == 0) {
        const int q = qt * 128 + w * 16 + ll;
        msb[((size_t)split * 4 + bb) * LQ + q] = mold;
        lsb[((size_t)split * 4 + bb) * LQ + q] = lsum;
    }
}

// ---------------------------------------------------------------------------
// Combine the 4 KV-split partials (layout matched to new attn blocking).
// ---------------------------------------------------------------------------
__global__ __launch_bounds__(512) void combine_kernel(
    const float* __restrict__ Opart, const float* __restrict__ msb,
    const float* __restrict__ lsb, float* __restrict__ out)
{
    const int blk = blockIdx.x;          // 256 blocks: 4 bb x 32 qt x 2 fg
    const int bb = blk & 3;
    const int qt = (blk >> 2) & 31;
    const int fg = blk >> 7;             // 0..1
    const int t = threadIdx.x;
    const int w = t >> 6, l = t & 63, lg = (l >> 4) & 3, ll = l & 15;

    const int q = qt * 128 + w * 16 + ll;
    float ms[NSPLIT], ls[NSPLIT];
#pragma unroll
    for (int s = 0; s < NSPLIT; ++s) {
        ms[s] = msb[((size_t)s * 4 + bb) * LQ + q];
        ls[s] = lsb[((size_t)s * 4 + bb) * LQ + q];
    }
    float mM = fmaxf(fmaxf(ms[0], ms[1]), fmaxf(ms[2], ms[3]));
    float wsp[NSPLIT];
    float L = 0.f;
#pragma unroll
    for (int s = 0; s < NSPLIT; ++s) {
        wsp[s] = exp2f(ms[s] - mM);
        L += ls[s] * wsp[s];
    }
    const float inv = 1.f / L;
#pragma unroll
    for (int fi = 0; fi < 4; ++fi) {
        const int f = fg * 4 + fi;
        f32x4 acc = {0.f, 0.f, 0.f, 0.f};
#pragma unroll
        for (int s = 0; s < NSPLIT; ++s) {
            const size_t ob = (((size_t)s * 4 + bb) * 32 + qt) * 8 + w;
            float4v ov = *(const float4v*)&Opart[(ob * 8 + f) * 256 + l * 4];
#pragma unroll
            for (int j = 0; j < 4; ++j) acc[j] += ov[j] * wsp[s];
        }
#pragma unroll
        for (int j = 0; j < 4; ++j) acc[j] *= inv;
        *(float4v*)&out[((size_t)bb * LQ + q) * H_ + f * 16 + lg * 4] = acc;
    }
}

extern "C" void kernel_launch(void* const* d_in, const int* in_sizes, int n_in,
                              void* d_out, int out_size, void* d_ws, size_t ws_size,
                              hipStream_t stream) {
    const float* x  = (const float*)d_in[0];
    const float* z  = (const float*)d_in[1];
    const float* Wq = (const float*)d_in[2];
    const float* Wk = (const float*)d_in[3];
    const float* Wv = (const float*)d_in[4];
    float* out = (float*)d_out;

    const size_t NQ = (size_t)B_ * LQ * H_;   // 2,097,152
    unsigned short* qhi = (unsigned short*)d_ws;
    unsigned short* qlo = qhi + NQ;
    unsigned short* khi = qlo + NQ;
    unsigned short* klo = khi + NQ;
    unsigned short* vtp = klo + NQ;           // 5 * 4 MiB = 20 MiB
    float* Opart = (float*)(vtp + NQ);        // NSPLIT * NQ f32 = 32 MiB
    float* msb   = Opart + (size_t)NSPLIT * NQ;
    float* lsb   = msb + (size_t)NSPLIT * B_ * LQ;
    unsigned short* wqh = (unsigned short*)(lsb + (size_t)NSPLIT * B_ * LQ);
    unsigned short* wql = wqh + WELEM;
    unsigned short* wkh = wql + WELEM;
    unsigned short* wkl = wkh + WELEM;
    unsigned short* wvh = wkl + WELEM;        // +1.25 MiB

    convert_w_kernel<<<dim3(16, 3), 256, 0, stream>>>(Wq, Wk, Wv, wqh, wql, wkh, wkl, wvh);
    proj_kernel<<<dim3(256), 512, 0, stream>>>(x, z, wqh, wql, wkh, wkl, wvh,
                                               qhi, qlo, khi, klo, vtp);
    attn_kernel<<<dim3(512), 512, 0, stream>>>(qhi, qlo, khi, klo, vtp, Opart, msb, lsb);
    combine_kernel<<<dim3(256), 512, 0, stream>>>(Opart, msb, lsb, out);
}